// Round 1
// baseline (611.400 us; speedup 1.0000x reference)
//
#include <hip/hip_runtime.h>
#include <hip/hip_bf16.h>
#include <cstdint>
#include <cstddef>

typedef __bf16 bf16_t;
typedef bf16_t bf16x4 __attribute__((ext_vector_type(4)));
typedef bf16_t bf16x8 __attribute__((ext_vector_type(8)));
typedef float  f32x4  __attribute__((ext_vector_type(4)));

#define FWHT_N 4096
#define BM 128
#define BN 128
#define BK 32

// ---------------------------------------------------------------------------
// Kernel 1: normalized FWHT along rows of W (fp32 in LDS), emit bf16 W'
// W' = H * W[o,:] / 64  (Sylvester H symmetric => x@W'^T == fwht(x)@W^T)
// ---------------------------------------------------------------------------
__global__ __launch_bounds__(256) void fwht_rows_bf16(const float* __restrict__ W,
                                                      bf16_t* __restrict__ Wt) {
    __shared__ float row[FWHT_N];
    const int r   = blockIdx.x;
    const int tid = threadIdx.x;

    const float4* src  = (const float4*)(W + (size_t)r * FWHT_N);
    float4*       rowv = (float4*)row;
#pragma unroll
    for (int i = 0; i < 4; ++i) rowv[tid + 256 * i] = src[tid + 256 * i];
    __syncthreads();

    for (int h = 1; h < FWHT_N; h <<= 1) {
#pragma unroll
        for (int it = 0; it < 8; ++it) {
            const int p = tid + 256 * it;                      // pair index 0..2047
            const int i = ((p & ~(h - 1)) << 1) | (p & (h - 1));
            const float a = row[i];
            const float b = row[i + h];
            row[i]     = a + b;
            row[i + h] = a - b;
        }
        __syncthreads();
    }

    const float s = 0.015625f;  // 1/sqrt(4096)
    bf16x4* dst = (bf16x4*)(Wt + (size_t)r * FWHT_N);
#pragma unroll
    for (int i = 0; i < 4; ++i) {
        const float4 v = rowv[tid + 256 * i];
        bf16x4 o;
        o[0] = (bf16_t)(v.x * s);
        o[1] = (bf16_t)(v.y * s);
        o[2] = (bf16_t)(v.z * s);
        o[3] = (bf16_t)(v.w * s);
        dst[tid + 256 * i] = o;
    }
}

// ---------------------------------------------------------------------------
// Kernel 2: x fp32 -> bf16 (vectorized)
// ---------------------------------------------------------------------------
__global__ __launch_bounds__(256) void cvt_f32_bf16(const float4* __restrict__ x,
                                                    bf16x4* __restrict__ y) {
    const size_t i = (size_t)blockIdx.x * 256 + threadIdx.x;
    const float4 v = x[i];
    bf16x4 o;
    o[0] = (bf16_t)v.x;
    o[1] = (bf16_t)v.y;
    o[2] = (bf16_t)v.z;
    o[3] = (bf16_t)v.w;
    y[i] = o;
}

// ---------------------------------------------------------------------------
// Kernel 3: C[M,N] = A[M,K] * B[N,K]^T + bias   (bf16 in, fp32 out)
// m97 structure: 128x128 tile, BK=32, global_load_lds width 16, 2-barrier loop
// ---------------------------------------------------------------------------
__device__ __forceinline__ void g2lds16(const bf16_t* g, bf16_t* l) {
    __builtin_amdgcn_global_load_lds((__attribute__((address_space(1))) void*)g,
                                     (__attribute__((address_space(3))) void*)l,
                                     16, 0, 0);
}

__global__ __launch_bounds__(256) void gemm_bt_bias(const bf16_t* __restrict__ A,
                                                    const bf16_t* __restrict__ Bm,
                                                    const float* __restrict__ bias,
                                                    float* __restrict__ C,
                                                    int M, int N, int K) {
    __shared__ __align__(16) bf16_t As[BM * BK];  // [128][32], unpadded (global_load_lds)
    __shared__ __align__(16) bf16_t Bs[BN * BK];  // [128][32]

    const int tid  = threadIdx.x;
    const int wave = tid >> 6;
    const int lane = tid & 63;
    const int quad = lane >> 4;
    const int l16  = lane & 15;

    const int bn = blockIdx.x;
    const int bm = blockIdx.y;
    const int m0 = bm * BM;
    const int n0 = bn * BN;

    // wave -> 64x64 quadrant
    const int wm = (wave >> 1) * 64;
    const int wn = (wave & 1) * 64;

    // staging: thread tid loads 16B: row = tid/4 (then +64), kcol = (tid%4)*8
    const int ldrow = tid >> 2;
    const int ldcol = (tid & 3) * 8;

    const bf16_t* gA = A  + (size_t)(m0 + ldrow) * K + ldcol;
    const bf16_t* gB = Bm + (size_t)(n0 + ldrow) * K + ldcol;
    const size_t half = (size_t)64 * K;

    bf16_t* lA = &As[tid * 8];
    bf16_t* lB = &Bs[tid * 8];

    f32x4 acc[4][4] = {};

    for (int k0 = 0; k0 < K; k0 += BK) {
        g2lds16(gA,        lA);
        g2lds16(gA + half, lA + 2048);
        g2lds16(gB,        lB);
        g2lds16(gB + half, lB + 2048);
        gA += BK;
        gB += BK;
        __syncthreads();  // drains vmcnt(0): LDS tiles ready

        bf16x8 af[4], bfr[4];
#pragma unroll
        for (int mi = 0; mi < 4; ++mi)
            af[mi] = *(const bf16x8*)&As[(wm + mi * 16 + l16) * BK + quad * 8];
#pragma unroll
        for (int ni = 0; ni < 4; ++ni)
            bfr[ni] = *(const bf16x8*)&Bs[(wn + ni * 16 + l16) * BK + quad * 8];

#pragma unroll
        for (int mi = 0; mi < 4; ++mi)
#pragma unroll
            for (int ni = 0; ni < 4; ++ni)
                acc[mi][ni] = __builtin_amdgcn_mfma_f32_16x16x32_bf16(
                    af[mi], bfr[ni], acc[mi][ni], 0, 0, 0);

        __syncthreads();  // all reads done before next iteration's stores
    }

    // Epilogue: C/D layout col=lane&15, row=quad*4+reg (m89/m91-verified)
    const int crow = quad * 4;
#pragma unroll
    for (int ni = 0; ni < 4; ++ni) {
        const int n  = n0 + wn + ni * 16 + l16;
        const float bv = bias[n];
#pragma unroll
        for (int mi = 0; mi < 4; ++mi) {
            const int mb = m0 + wm + mi * 16 + crow;
#pragma unroll
            for (int r = 0; r < 4; ++r)
                C[(size_t)(mb + r) * N + n] = acc[mi][ni][r] + bv;
        }
    }
}

// ---------------------------------------------------------------------------
extern "C" void kernel_launch(void* const* d_in, const int* in_sizes, int n_in,
                              void* d_out, int out_size, void* d_ws, size_t ws_size,
                              hipStream_t stream) {
    const float* x = (const float*)d_in[0];   // [B,S,K] fp32
    const float* W = (const float*)d_in[1];   // [N,K]   fp32
    const float* b = (const float*)d_in[2];   // [N]     fp32
    float* out = (float*)d_out;               // [B,S,N] fp32

    const int K = 4096;
    const int N = 4096;
    const int M = in_sizes[0] / K;            // 8192

    // workspace: xb (M*K bf16 = 64 MiB) | Wt (N*K bf16 = 32 MiB)
    bf16_t* xb = (bf16_t*)d_ws;
    bf16_t* Wt = xb + (size_t)M * K;

    hipLaunchKernelGGL(fwht_rows_bf16, dim3(N), dim3(256), 0, stream, W, Wt);

    const int cvt_blocks = (int)(((size_t)M * K) / 4 / 256);  // 32768
    hipLaunchKernelGGL(cvt_f32_bf16, dim3(cvt_blocks), dim3(256), 0, stream,
                       (const float4*)x, (bf16x4*)xb);

    hipLaunchKernelGGL(gemm_bt_bias, dim3(N / BN, M / BM), dim3(256), 0, stream,
                       xb, Wt, b, out, M, N, K);
}

// Round 2
// 609.233 us; speedup vs baseline: 1.0036x; 1.0036x over previous
//
#include <hip/hip_runtime.h>
#include <hip/hip_bf16.h>
#include <cstdint>
#include <cstddef>

typedef __bf16 bf16_t;
typedef bf16_t bf16x4 __attribute__((ext_vector_type(4)));
typedef bf16_t bf16x8 __attribute__((ext_vector_type(8)));
typedef float  f32x4  __attribute__((ext_vector_type(4)));

#define FWHT_N 4096
#define BM 128
#define BN 128
#define BK 32

// ---------------------------------------------------------------------------
// 16-point in-register FWHT (4 radix-2 stages, unnormalized)
// ---------------------------------------------------------------------------
__device__ __forceinline__ void fwht16(float v[16]) {
#pragma unroll
    for (int h = 1; h < 16; h <<= 1) {
#pragma unroll
        for (int i = 0; i < 16; ++i) {
            if (!(i & h)) {
                const float a = v[i];
                const float b = v[i | h];
                v[i]     = a + b;
                v[i | h] = a - b;
            }
        }
    }
}

// padded LDS address: +1 word every 32 => all round patterns are 2-way (free)
__device__ __forceinline__ int pad(int i) { return i + (i >> 5); }

// ---------------------------------------------------------------------------
// Kernel 1: normalized FWHT along rows of W, emit bf16 W'
// 4096 = 16^3 -> 3 radix-16 register rounds, 2 LDS transposes, 2 syncs
// W' = H * W[o,:] / 64  (H symmetric => x@W'^T == fwht(x)@W^T)
// ---------------------------------------------------------------------------
__global__ __launch_bounds__(256) void fwht_rows_bf16(const float* __restrict__ W,
                                                      bf16_t* __restrict__ Wt) {
    __shared__ float lds[FWHT_N + (FWHT_N >> 5)];
    const int r = blockIdx.x;
    const int t = threadIdx.x;

    float v[16];

    // ---- round 0: bits 0-3, i = 16t + k (contiguous) ----
    const float4* src = (const float4*)(W + (size_t)r * FWHT_N + 16 * t);
    {
        const float4 a0 = src[0], a1 = src[1], a2 = src[2], a3 = src[3];
        v[0] = a0.x; v[1] = a0.y; v[2]  = a0.z; v[3]  = a0.w;
        v[4] = a1.x; v[5] = a1.y; v[6]  = a1.z; v[7]  = a1.w;
        v[8] = a2.x; v[9] = a2.y; v[10] = a2.z; v[11] = a2.w;
        v[12] = a3.x; v[13] = a3.y; v[14] = a3.z; v[15] = a3.w;
    }
    fwht16(v);
    {
        // addr = 16t + (t>>1) + k : contiguous 16, banks hit 2x per wave
        const int base = 16 * t + (t >> 1);
#pragma unroll
        for (int k = 0; k < 16; ++k) lds[base + k] = v[k];
    }
    __syncthreads();

    // ---- round 1: bits 4-7, i = (t>>4)*256 + (t&15) + 16k ----
    const int b1 = ((t >> 4) << 8) | (t & 15);
#pragma unroll
    for (int k = 0; k < 16; ++k) v[k] = lds[pad(b1 + (k << 4))];
    fwht16(v);
#pragma unroll
    for (int k = 0; k < 16; ++k) lds[pad(b1 + (k << 4))] = v[k];
    __syncthreads();

    // ---- round 2: bits 8-11, i = t + 256k ----
#pragma unroll
    for (int k = 0; k < 16; ++k) v[k] = lds[pad(t + (k << 8))];
    fwht16(v);

    const float s = 0.015625f;  // 1/sqrt(4096)
    bf16_t* dst = Wt + (size_t)r * FWHT_N + t;
#pragma unroll
    for (int k = 0; k < 16; ++k) dst[k << 8] = (bf16_t)(v[k] * s);
}

// ---------------------------------------------------------------------------
// Kernel 2: x fp32 -> bf16, 16B/lane stores
// ---------------------------------------------------------------------------
__global__ __launch_bounds__(256) void cvt_f32_bf16(const float4* __restrict__ x,
                                                    bf16x8* __restrict__ y) {
    const size_t i = (size_t)blockIdx.x * 256 + threadIdx.x;
    const float4 a = x[2 * i];
    const float4 b = x[2 * i + 1];
    bf16x8 o;
    o[0] = (bf16_t)a.x; o[1] = (bf16_t)a.y; o[2] = (bf16_t)a.z; o[3] = (bf16_t)a.w;
    o[4] = (bf16_t)b.x; o[5] = (bf16_t)b.y; o[6] = (bf16_t)b.z; o[7] = (bf16_t)b.w;
    y[i] = o;
}

// ---------------------------------------------------------------------------
// Kernel 3: C[M,N] = A[M,K] * B[N,K]^T + bias   (bf16 in, fp32 out)
// m97 structure: 128x128 tile, BK=32, global_load_lds width 16, 2-barrier loop
// ---------------------------------------------------------------------------
__device__ __forceinline__ void g2lds16(const bf16_t* g, bf16_t* l) {
    __builtin_amdgcn_global_load_lds((__attribute__((address_space(1))) void*)g,
                                     (__attribute__((address_space(3))) void*)l,
                                     16, 0, 0);
}

__global__ __launch_bounds__(256) void gemm_bt_bias(const bf16_t* __restrict__ A,
                                                    const bf16_t* __restrict__ Bm,
                                                    const float* __restrict__ bias,
                                                    float* __restrict__ C,
                                                    int M, int N, int K) {
    __shared__ __align__(16) bf16_t As[BM * BK];  // [128][32], unpadded (global_load_lds)
    __shared__ __align__(16) bf16_t Bs[BN * BK];  // [128][32]

    const int tid  = threadIdx.x;
    const int wave = tid >> 6;
    const int lane = tid & 63;
    const int quad = lane >> 4;
    const int l16  = lane & 15;

    const int bn = blockIdx.x;
    const int bm = blockIdx.y;
    const int m0 = bm * BM;
    const int n0 = bn * BN;

    const int wm = (wave >> 1) * 64;
    const int wn = (wave & 1) * 64;

    const int ldrow = tid >> 2;
    const int ldcol = (tid & 3) * 8;

    const bf16_t* gA = A  + (size_t)(m0 + ldrow) * K + ldcol;
    const bf16_t* gB = Bm + (size_t)(n0 + ldrow) * K + ldcol;
    const size_t half = (size_t)64 * K;

    bf16_t* lA = &As[tid * 8];
    bf16_t* lB = &Bs[tid * 8];

    f32x4 acc[4][4] = {};

    for (int k0 = 0; k0 < K; k0 += BK) {
        g2lds16(gA,        lA);
        g2lds16(gA + half, lA + 2048);
        g2lds16(gB,        lB);
        g2lds16(gB + half, lB + 2048);
        gA += BK;
        gB += BK;
        __syncthreads();

        bf16x8 af[4], bfr[4];
#pragma unroll
        for (int mi = 0; mi < 4; ++mi)
            af[mi] = *(const bf16x8*)&As[(wm + mi * 16 + l16) * BK + quad * 8];
#pragma unroll
        for (int ni = 0; ni < 4; ++ni)
            bfr[ni] = *(const bf16x8*)&Bs[(wn + ni * 16 + l16) * BK + quad * 8];

#pragma unroll
        for (int mi = 0; mi < 4; ++mi)
#pragma unroll
            for (int ni = 0; ni < 4; ++ni)
                acc[mi][ni] = __builtin_amdgcn_mfma_f32_16x16x32_bf16(
                    af[mi], bfr[ni], acc[mi][ni], 0, 0, 0);

        __syncthreads();
    }

    const int crow = quad * 4;
#pragma unroll
    for (int ni = 0; ni < 4; ++ni) {
        const int n  = n0 + wn + ni * 16 + l16;
        const float bv = bias[n];
#pragma unroll
        for (int mi = 0; mi < 4; ++mi) {
            const int mb = m0 + wm + mi * 16 + crow;
#pragma unroll
            for (int r = 0; r < 4; ++r)
                C[(size_t)(mb + r) * N + n] = acc[mi][ni][r] + bv;
        }
    }
}

// ---------------------------------------------------------------------------
extern "C" void kernel_launch(void* const* d_in, const int* in_sizes, int n_in,
                              void* d_out, int out_size, void* d_ws, size_t ws_size,
                              hipStream_t stream) {
    const float* x = (const float*)d_in[0];   // [B,S,K] fp32
    const float* W = (const float*)d_in[1];   // [N,K]   fp32
    const float* b = (const float*)d_in[2];   // [N]     fp32
    float* out = (float*)d_out;               // [B,S,N] fp32

    const int K = 4096;
    const int N = 4096;
    const int M = in_sizes[0] / K;            // 8192

    bf16_t* xb = (bf16_t*)d_ws;               // M*K bf16 = 64 MiB
    bf16_t* Wt = xb + (size_t)M * K;          // N*K bf16 = 32 MiB

    hipLaunchKernelGGL(fwht_rows_bf16, dim3(N), dim3(256), 0, stream, W, Wt);

    const int cvt_blocks = (int)(((size_t)M * K) / 8 / 256);  // 16384
    hipLaunchKernelGGL(cvt_f32_bf16, dim3(cvt_blocks), dim3(256), 0, stream,
                       (const float4*)x, (bf16x8*)xb);

    hipLaunchKernelGGL(gemm_bt_bias, dim3(N / BN, M / BM), dim3(256), 0, stream,
                       xb, Wt, b, out, M, N, K);
}